// Round 11
// baseline (859.067 us; speedup 1.0000x reference)
//
#include <hip/hip_runtime.h>
#include <math.h>

#define NN 100000
#define NE 1000000
#define D 64
#define L 3
#define RVQ 3
#define CODES 16
#define BN_EPS 1e-5f
#define COMMIT_W 0.25f

#define GRID_A 2048   // blocks for bnstats kernel (fixed: partials + node mapping)

// ---------------- ws layout (in 4-byte units) ----------------
#define OFS_ROWPTR 0           // 100001 ints
#define OFS_CNT    100016      // 100000 ints
#define OFS_CURSOR 200032      // 100000 ints (reused as Wt scratch after CSR build)
#define OFS_BSUMS  300048      // 128 ints
#define OFS_BOFFS  300176      // 128 ints
#define OFS_STATS  300304      // 3*128 floats (sum[64],sumsq[64] per layer)
#define OFS_CSR    300800      // 1000000 ints
#define OFS_HA     1300800     // 6400000 floats
#define OFS_HB     7700800     // 6400000 floats
#define OFS_XLOC   14100800    // 6400000 floats
#define OFS_PART   20500800    // 2048*128 floats = 262144
// total = 20,762,944 * 4 B ~= 83 MB
// mean buffer lives in d_out's pred region (scratch until k_head overwrites).

// ---------------- d_out layout (floats) ----------------
#define OUT_PRED   0
#define OUT_COMMIT (NN * D)                       // 6,400,000
#define OUT_IDS    (NN * D + 1)                   // 6,400,001
#define OUT_GNN    (NN * D + 1 + NN * (L * RVQ))  // 7,300,001

static __device__ __forceinline__ float waveSum(float v) {
    #pragma unroll
    for (int off = 32; off; off >>= 1) v += __shfl_xor(v, off, 64);
    return v;
}

// DPP quad-permute helpers: value from lane^1 / lane^2 within each quad.
static __device__ __forceinline__ float qxor1(float v) {
    return __int_as_float(__builtin_amdgcn_mov_dpp(__float_as_int(v), 0xB1, 0xF, 0xF, 1));
}
static __device__ __forceinline__ float qxor2(float v) {
    return __int_as_float(__builtin_amdgcn_mov_dpp(__float_as_int(v), 0x4E, 0xF, 0xF, 1));
}

// ---------------- CSR build ----------------
__global__ void k_count(const int* __restrict__ dst, int* __restrict__ cnt) {
    int e = blockIdx.x * blockDim.x + threadIdx.x;
    if (e < NE) atomicAdd(&cnt[dst[e]], 1);
}

#define SCAN_B 1024
__global__ void k_scan1(const int* __restrict__ cnt, int* __restrict__ rowptr,
                        int* __restrict__ bsums) {
    __shared__ int sm[SCAN_B];
    int t = threadIdx.x;
    int i = blockIdx.x * SCAN_B + t;
    int v = (i < NN) ? cnt[i] : 0;
    sm[t] = v;
    __syncthreads();
    for (int off = 1; off < SCAN_B; off <<= 1) {
        int add = (t >= off) ? sm[t - off] : 0;
        __syncthreads();
        sm[t] += add;
        __syncthreads();
    }
    if (i < NN) rowptr[i + 1] = sm[t];
    if (t == SCAN_B - 1) bsums[blockIdx.x] = sm[t];
}

__global__ void k_scan2(const int* __restrict__ bsums, int* __restrict__ boffs, int nb) {
    __shared__ int sm[SCAN_B];
    int t = threadIdx.x;
    int orig = (t < nb) ? bsums[t] : 0;
    sm[t] = orig;
    __syncthreads();
    for (int off = 1; off < SCAN_B; off <<= 1) {
        int add = (t >= off) ? sm[t - off] : 0;
        __syncthreads();
        sm[t] += add;
        __syncthreads();
    }
    if (t < nb) boffs[t] = sm[t] - orig;  // exclusive
}

__global__ void k_scan3(int* __restrict__ rowptr, const int* __restrict__ boffs) {
    int i = blockIdx.x * SCAN_B + threadIdx.x;
    if (i < NN) rowptr[i + 1] += boffs[blockIdx.x];
    if (i == 0) rowptr[0] = 0;
}

__global__ void k_cursor(const int* __restrict__ rowptr, int* __restrict__ cursor) {
    int i = blockIdx.x * blockDim.x + threadIdx.x;
    if (i < NN) cursor[i] = rowptr[i];
}

// dst-range-partitioned fill. R10 post-mortem: the old whole-range scatter
// wrote 69 MB to HBM for a 4 MB payload (17x line amplification: random 4B
// stores across 4MB + streaming reads evicting partial dirty lines across 8
// non-coherent XCD L2s) -> 72us at ~1TB/s random-write BW. Here piece p =
// blockIdx%8 (round-robin dispatch -> all of piece p's blocks on XCD p)
// handles dst in [p*12500, (p+1)*12500): its write region is a CONTIGUOUS
// ~512KB slice of csr (rowptr monotonic) + 50KB cursor slice, resident in
// that XCD's L2 and touched by no other XCD -> lines fill before eviction.
// Cost: every piece scans all edges (8x reads, streaming+nt ~ 64MB ~ 11us).
// Fill order within a row changes, but k_sortrows canonicalizes -> CSR and
// all downstream outputs BIT-IDENTICAL.
#define FILL_P   8
#define FILL_BPP 64   // blocks per piece
__global__ __launch_bounds__(256) void k_fill(
    const int* __restrict__ src, const int* __restrict__ dst,
    int* __restrict__ cursor, int* __restrict__ csr_src) {
    int piece = blockIdx.x & (FILL_P - 1);      // same XCD for a given piece
    int bip   = blockIdx.x / FILL_P;
    int lo = piece * (NN / FILL_P);
    int hi = lo + (NN / FILL_P);
    int e0 = bip * 256 + threadIdx.x;
    const int stride = FILL_BPP * 256;
    for (int e = e0; e < NE; e += stride) {
        int d = __builtin_nontemporal_load(&dst[e]);
        if (d >= lo && d < hi) {
            int p = atomicAdd(&cursor[d], 1);
            csr_src[p] = __builtin_nontemporal_load(&src[e]);
        }
    }
}

// Canonicalize row order so the neighbor-sum order is deterministic.
__global__ void k_sortrows(const int* __restrict__ rowptr, int* __restrict__ csr) {
    int n = blockIdx.x * blockDim.x + threadIdx.x;
    if (n >= NN) return;
    int r0 = rowptr[n], r1 = rowptr[n + 1];
    for (int i = r0 + 1; i < r1; ++i) {
        int v = csr[i];
        int j = i - 1;
        while (j >= r0 && csr[j] > v) { csr[j + 1] = csr[j]; --j; }
        csr[j + 1] = v;
    }
}

// ---------------- Gather: mean of neighbor rows -> mean_out ----------------
__global__ __launch_bounds__(256) void k_gather(
    const float* __restrict__ h, const int* __restrict__ rowptr,
    const int* __restrict__ csr_src, float* __restrict__ mean_out) {
    int t = threadIdx.x;
    int lane = t & 63, wid = t >> 6;
    int n = blockIdx.x * 4 + wid;
    if (n >= NN) return;

    int r0 = rowptr[n], r1 = rowptr[n + 1];
    float s = 0.f;
    for (int base = r0; base < r1; base += 64) {
        int last = r1 - 1;
        int ii = base + lane;
        int idx = csr_src[(ii <= last) ? ii : last];  // coalesced, clamped
        int m = r1 - base;
        if (m > 64) m = 64;
        int j = 0;
        for (; j + 8 <= m; j += 8) {
            int i0 = __shfl(idx, j + 0, 64), i1 = __shfl(idx, j + 1, 64);
            int i2 = __shfl(idx, j + 2, 64), i3 = __shfl(idx, j + 3, 64);
            int i4 = __shfl(idx, j + 4, 64), i5 = __shfl(idx, j + 5, 64);
            int i6 = __shfl(idx, j + 6, 64), i7 = __shfl(idx, j + 7, 64);
            float v0 = h[i0 * D + lane], v1 = h[i1 * D + lane];
            float v2 = h[i2 * D + lane], v3 = h[i3 * D + lane];
            float v4 = h[i4 * D + lane], v5 = h[i5 * D + lane];
            float v6 = h[i6 * D + lane], v7 = h[i7 * D + lane];
            s += v0; s += v1; s += v2; s += v3;
            s += v4; s += v5; s += v6; s += v7;
        }
        for (; j + 4 <= m; j += 4) {
            int i0 = __shfl(idx, j + 0, 64), i1 = __shfl(idx, j + 1, 64);
            int i2 = __shfl(idx, j + 2, 64), i3 = __shfl(idx, j + 3, 64);
            float v0 = h[i0 * D + lane], v1 = h[i1 * D + lane];
            float v2 = h[i2 * D + lane], v3 = h[i3 * D + lane];
            s += v0; s += v1; s += v2; s += v3;
        }
        for (; j < m; ++j) {
            int i0 = __shfl(idx, j, 64);
            s += h[i0 * D + lane];
        }
    }
    float deg = (float)(r1 - r0);
    mean_out[n * D + lane] = s / fmaxf(deg, 1.0f);
}

// Weight transpose pre-pass: wt[m][o][k] = Wm[k*D+o], so per-output rows
// are contiguous for scalar (s_load) access. 48 KB per layer, ~2us.
__global__ void k_wt(const float* __restrict__ Wa, const float* __restrict__ Wr,
                     const float* __restrict__ Wl, float* __restrict__ wt) {
    int i = blockIdx.x * 256 + threadIdx.x;
    if (i >= 3 * D * D) return;
    int m = i >> 12;
    int o = (i >> 6) & 63;
    int k = i & 63;
    const float* W = (m == 0) ? Wa : (m == 1) ? Wr : Wl;
    wt[i] = W[k * D + o];
}

// ---------------- Matvec: SAGE transform + skip linear ----------------
// lane=node, weights scalar (SGPR), streamed activations (R10, passed):
// live set ~40 VGPR beats the stingiest allocator grant; DS 32 b128/thread;
// FMA order identical across rounds -> hp BIT-IDENTICAL.
__global__ __launch_bounds__(512) void k_matvec(
    const float* __restrict__ mean, const float* __restrict__ h,
    float* __restrict__ hp, const float* __restrict__ wt,
    const float* __restrict__ ba, const float* __restrict__ bl) {
    __shared__ alignas(16) float ls[64 * 132];  // 33792 B; reused by epilogue
    int t = threadIdx.x, lane = t & 63, wid = t >> 6;
    int tb = blockIdx.x * 64;

    // ---- stage 64 node rows of mean and h, coalesced float4 ----
    #pragma unroll
    for (int s = 0; s < 2; ++s) {
        int fid = s * 512 + t;          // 0..1023 float4 slots
        int node = fid >> 4, c = (fid & 15) * 4;
        int gn = tb + node; if (gn > NN - 1) gn = NN - 1;   // tail clamp
        float4 vm = *(const float4*)(mean + (size_t)gn * D + c);
        float4 vh = *(const float4*)(h    + (size_t)gn * D + c);
        *(float4*)&ls[node * 132 + c]      = vm;
        *(float4*)&ls[node * 132 + 64 + c] = vh;
    }
    __syncthreads();

    int ob = __builtin_amdgcn_readfirstlane(wid * 8);  // wave's o-base (uniform)

    float am[8], rm[8], lm[8];
    #pragma unroll
    for (int oi = 0; oi < 8; ++oi) { am[oi] = 0.f; rm[oi] = 0.f; lm[oi] = 0.f; }

    #pragma unroll 1
    for (int g = 0; g < 16; ++g) {      // k-groups of 4: act floats streamed
        float4 m4 = *(const float4*)&ls[lane * 132 + g * 4];
        float4 h4 = *(const float4*)&ls[lane * 132 + 64 + g * 4];
        #pragma unroll
        for (int oi = 0; oi < 8; ++oi) {
            const float* wa = wt +        (ob + oi) * D + g * 4;  // uniform
            const float* wr = wt + 4096 + (ob + oi) * D + g * 4;
            const float* wl = wt + 8192 + (ob + oi) * D + g * 4;
            am[oi] += m4.x * wa[0]; rm[oi] += h4.x * wr[0]; lm[oi] += h4.x * wl[0];
            am[oi] += m4.y * wa[1]; rm[oi] += h4.y * wr[1]; lm[oi] += h4.y * wl[1];
            am[oi] += m4.z * wa[2]; rm[oi] += h4.z * wr[2]; lm[oi] += h4.z * wl[2];
            am[oi] += m4.w * wa[3]; rm[oi] += h4.w * wr[3]; lm[oi] += h4.w * wl[3];
        }
    }
    __syncthreads();   // all act reads done before ls is overwritten

    // transpose sage/lm into LDS: writer lane = node; stride 65 -> bank
    // (lane + o) % 32, 2 lanes/bank = free
    #pragma unroll
    for (int oi = 0; oi < 8; ++oi) {
        float bav = ba[ob + oi];                   // uniform scalar
        float sage = am[oi] + bav + rm[oi];        // (am+bav)+rm, exact old order
        ls[lane * 65 + (ob + oi)]        = sage;
        ls[4160 + lane * 65 + (ob + oi)] = lm[oi];
    }
    __syncthreads();

    // epilogue: lane = o; wave handles 8 nodes; EXACT old butterfly + chain
    float blv = bl[lane];
    #pragma unroll
    for (int i = 0; i < 8; ++i) {
        int node = wid * 8 + i;
        float sage = ls[node * 65 + lane];
        float lv   = ls[4160 + node * 65 + lane];
        float ss = waveSum(sage * sage);
        float inv = 1.0f / (sqrtf(ss) + 1e-12f);
        float hpv = sage * inv + lv + blv;
        int gn = tb + node;
        if (gn < NN) hp[(size_t)gn * D + lane] = hpv;
    }
}

// BN stat partials over the finished hp buffer. Replicates the ORIGINAL
// k_matvec accumulation order exactly -> stats BIT-IDENTICAL.
__global__ __launch_bounds__(256) void k_bnstats(
    const float* __restrict__ hp, float* __restrict__ partials) {
    __shared__ float red[2][4][D];
    int t = threadIdx.x, lane = t & 63, wid = t >> 6;
    int wg = blockIdx.x * 4 + wid;
    const int wstep = GRID_A * 4;
    float accS = 0.f, accQ = 0.f;
    for (int n = wg; n < NN; n += wstep) {
        float hpv = hp[(size_t)n * D + lane];
        accS += hpv;
        accQ += hpv * hpv;
    }
    red[0][wid][lane] = accS;
    red[1][wid][lane] = accQ;
    __syncthreads();
    if (wid == 0) {
        float s0 = (red[0][0][lane] + red[0][1][lane]) + (red[0][2][lane] + red[0][3][lane]);
        float q0 = (red[1][0][lane] + red[1][1][lane]) + (red[1][2][lane] + red[1][3][lane]);
        partials[blockIdx.x * 128 + lane]      = s0;
        partials[blockIdx.x * 128 + 64 + lane] = q0;
    }
}

// Parallel deterministic reduction of BN stat partials.
__global__ __launch_bounds__(256) void k_red_stats(
    const float* __restrict__ part, float* __restrict__ stats) {
    __shared__ float sm[256];
    int c = blockIdx.x;      // 0..127
    int i = threadIdx.x;     // 0..255
    float s = 0.f;
    #pragma unroll
    for (int k = 0; k < 8; ++k)
        s += part[(size_t)(i * 8 + k) * 128 + c];
    sm[i] = s;
    __syncthreads();
    #pragma unroll
    for (int off = 128; off >= 1; off >>= 1) {
        if (i < off) sm[i] += sm[i + off];
        __syncthreads();
    }
    if (i == 0) stats[c] = sm[0];
}

// ---------------- Layer part B: BN + ReLU + x_local accumulate + residual VQ
// Quad-per-node scheme: residual in registers, DPP quad reduces, serial
// first-max argmax; bit-identical sims to the wave-per-node original.
#define CBSTRIDE 68
__global__ __launch_bounds__(256) void k_layer_b(
    float* __restrict__ hp,              // in: pre-BN h'; out: post-ReLU h
    const float* __restrict__ stats,
    const float* __restrict__ gamma, const float* __restrict__ beta,
    const float* __restrict__ cbs,       // [RVQ][CODES][D] for this layer
    float* __restrict__ x_local,
    float* __restrict__ ids_out,         // [NN][L*RVQ] region base
    int layer, float* __restrict__ commit, int first_layer) {
    __shared__ alignas(16) float scb[RVQ * CODES * CBSTRIDE];
    __shared__ alignas(16) float sscale[D];
    __shared__ alignas(16) float sshift[D];
    __shared__ float sred[4];
    int t = threadIdx.x, lane = t & 63, wid = t >> 6;

    // normalize codebook rows into LDS (identical math to before)
    for (int row = wid; row < RVQ * CODES; row += 4) {
        float v = cbs[row * D + lane];
        float ss = waveSum(v * v);
        scb[row * CBSTRIDE + lane] = v / (sqrtf(ss) + 1e-12f);
    }
    // BN scale/shift per channel
    if (t < D) {
        float mu = stats[t] * (1.0f / NN);
        float var = stats[64 + t] * (1.0f / NN) - mu * mu;
        float scale = rsqrtf(var + BN_EPS) * gamma[t];
        sscale[t] = scale;
        sshift[t] = beta[t] - mu * scale;
    }
    __syncthreads();

    int gid = blockIdx.x * 256 + t;
    int node = gid >> 2;      // one node per quad of lanes
    int part = t & 3;         // which 16-channel slice this lane owns
    float closs = 0.f;

    if (node < NN) {
        float res[16];
        size_t base = (size_t)node * D + part * 16;
        const float4* hr = (const float4*)(hp + base);
        float4* hw = (float4*)(hp + base);
        float4* xw = (float4*)(x_local + base);
        const float4* scp = (const float4*)(sscale + part * 16);
        const float4* shp = (const float4*)(sshift + part * 16);

        #pragma unroll
        for (int i = 0; i < 4; ++i) {
            float4 v = hr[i];
            float4 sc = scp[i], sh = shp[i];
            float4 hn;
            hn.x = fmaxf(v.x * sc.x + sh.x, 0.f);
            hn.y = fmaxf(v.y * sc.y + sh.y, 0.f);
            hn.z = fmaxf(v.z * sc.z + sh.z, 0.f);
            hn.w = fmaxf(v.w * sc.w + sh.w, 0.f);
            hw[i] = hn;
            if (first_layer) {
                xw[i] = hn;
            } else {
                float4 xl = xw[i];
                xl.x += hn.x; xl.y += hn.y; xl.z += hn.z; xl.w += hn.w;
                xw[i] = xl;
            }
            res[4 * i + 0] = hn.x; res[4 * i + 1] = hn.y;
            res[4 * i + 2] = hn.z; res[4 * i + 3] = hn.w;
        }

        int bis[RVQ];
        #pragma unroll
        for (int r = 0; r < RVQ; ++r) {
            float sims[CODES];
            #pragma unroll
            for (int j = 0; j < CODES; ++j) {
                const float* cr = &scb[(r * CODES + j) * CBSTRIDE + part * 16];
                float4 c0 = *(const float4*)(cr + 0);
                float4 c1 = *(const float4*)(cr + 4);
                float4 c2 = *(const float4*)(cr + 8);
                float4 c3 = *(const float4*)(cr + 12);
                float a = res[0] * c0.x;
                a += res[1] * c0.y;  a += res[2] * c0.z;  a += res[3] * c0.w;
                a += res[4] * c1.x;  a += res[5] * c1.y;  a += res[6] * c1.z;  a += res[7] * c1.w;
                a += res[8] * c2.x;  a += res[9] * c2.y;  a += res[10] * c2.z; a += res[11] * c2.w;
                a += res[12] * c3.x; a += res[13] * c3.y; a += res[14] * c3.z; a += res[15] * c3.w;
                float b = a + qxor1(a);
                sims[j] = b + qxor2(b);
            }
            float bv = sims[0];
            int bi = 0;
            #pragma unroll
            for (int j = 1; j < CODES; ++j)
                if (sims[j] > bv) { bv = sims[j]; bi = j; }

            const float* qr = &scb[(r * CODES + bi) * CBSTRIDE + part * 16];
            #pragma unroll
            for (int i = 0; i < 4; ++i) {
                float4 q = *(const float4*)(qr + 4 * i);
                float d0 = q.x - res[4 * i + 0]; closs += d0 * d0; res[4 * i + 0] = -d0;
                float d1 = q.y - res[4 * i + 1]; closs += d1 * d1; res[4 * i + 1] = -d1;
                float d2 = q.z - res[4 * i + 2]; closs += d2 * d2; res[4 * i + 2] = -d2;
                float d3 = q.w - res[4 * i + 3]; closs += d3 * d3; res[4 * i + 3] = -d3;
            }
            bis[r] = bi;
        }
        if (part == 0) {
            ids_out[(size_t)node * (L * RVQ) + layer * RVQ + 0] = (float)bis[0];
            ids_out[(size_t)node * (L * RVQ) + layer * RVQ + 1] = (float)bis[1];
            ids_out[(size_t)node * (L * RVQ) + layer * RVQ + 2] = (float)bis[2];
        }
    }

    closs = waveSum(closs);
    if (lane == 0) sred[wid] = closs;
    __syncthreads();
    if (t == 0) {
        float tot = (sred[0] + sred[1]) + (sred[2] + sred[3]);
        atomicAdd(commit, tot * (COMMIT_W / (float)(NN * D)));
    }
}

// ---------------- Heads ----------------
__global__ __launch_bounds__(256, 2) void k_head(
    const float* __restrict__ x_local,
    const float* __restrict__ Wp, const float* __restrict__ bp,
    const float* __restrict__ Wg, const float* __restrict__ bg,
    float* __restrict__ pred, float* __restrict__ gnn) {
    int t = threadIdx.x, lane = t & 63, wid = t >> 6;
    int jsafe = (lane < 9) ? lane : 0;

    float wp[D], wg[D];
    #pragma unroll
    for (int k = 0; k < D; ++k) {
        wp[k] = Wp[k * D + lane];
        wg[k] = Wg[k * 9 + jsafe];
    }
    float bpv = bp[lane], bgv = bg[jsafe];

    int w = blockIdx.x * 4 + wid;
    int wstep = gridDim.x * 4;
    for (int n = w; n < NN; n += wstep) {
        int nu = __builtin_amdgcn_readfirstlane(n);
        const float4* xrow = (const float4*)(x_local + (size_t)nu * D);
        float p = 0.f, g = 0.f;
        #pragma unroll
        for (int j = 0; j < 16; ++j) {
            float4 x4 = xrow[j];
            p += x4.x * wp[4 * j + 0]; g += x4.x * wg[4 * j + 0];
            p += x4.y * wp[4 * j + 1]; g += x4.y * wg[4 * j + 1];
            p += x4.z * wp[4 * j + 2]; g += x4.z * wg[4 * j + 2];
            p += x4.w * wp[4 * j + 3]; g += x4.w * wg[4 * j + 3];
        }
        pred[(size_t)n * D + lane] = p + bpv;
        if (lane < 9) gnn[(size_t)n * 9 + lane] = g + bgv;
    }
}

extern "C" void kernel_launch(void* const* d_in, const int* in_sizes, int n_in,
                              void* d_out, int out_size, void* d_ws, size_t ws_size,
                              hipStream_t stream) {
    const float* x   = (const float*)d_in[0];
    const int* ei    = (const int*)d_in[1];
    const float* Wa  = (const float*)d_in[2];
    const float* ba  = (const float*)d_in[3];
    const float* Wr  = (const float*)d_in[4];
    const float* Wl  = (const float*)d_in[5];
    const float* bl  = (const float*)d_in[6];
    const float* gamma = (const float*)d_in[7];
    const float* beta  = (const float*)d_in[8];
    const float* cbs = (const float*)d_in[9];
    const float* Wp  = (const float*)d_in[10];
    const float* bp  = (const float*)d_in[11];
    const float* Wg  = (const float*)d_in[12];
    const float* bg  = (const float*)d_in[13];

    const int* src = ei;
    const int* dst = ei + NE;

    int*   ws_i  = (int*)d_ws;
    float* ws_f  = (float*)d_ws;
    int* rowptr  = ws_i + OFS_ROWPTR;
    int* cnt     = ws_i + OFS_CNT;
    int* cursor  = ws_i + OFS_CURSOR;
    int* bsums   = ws_i + OFS_BSUMS;
    int* boffs   = ws_i + OFS_BOFFS;
    float* stats = ws_f + OFS_STATS;
    int* csr_src = ws_i + OFS_CSR;
    float* hA    = ws_f + OFS_HA;
    float* hB    = ws_f + OFS_HB;
    float* xloc  = ws_f + OFS_XLOC;
    float* part  = ws_f + OFS_PART;
    float* wtbuf = ws_f + OFS_CURSOR;   // cursor scratch reused after CSR build

    float* out    = (float*)d_out;
    float* pred   = out + OUT_PRED;
    float* commit = out + OUT_COMMIT;
    float* ids    = out + OUT_IDS;
    float* gnn    = out + OUT_GNN;

    // mean buffer: reuse the pred region of d_out as scratch during the
    // layer loop (k_head fully overwrites it at the end).
    float* meanb = pred;

    hipMemsetAsync(cnt, 0, NN * sizeof(int), stream);
    hipMemsetAsync(commit, 0, sizeof(float), stream);

    // CSR build
    k_count<<<(NE + 255) / 256, 256, 0, stream>>>(dst, cnt);
    int nscan = (NN + SCAN_B - 1) / SCAN_B;  // 98
    k_scan1<<<nscan, SCAN_B, 0, stream>>>(cnt, rowptr, bsums);
    k_scan2<<<1, SCAN_B, 0, stream>>>(bsums, boffs, nscan);
    k_scan3<<<nscan, SCAN_B, 0, stream>>>(rowptr, boffs);
    k_cursor<<<(NN + 1023) / 1024, 1024, 0, stream>>>(rowptr, cursor);
    k_fill<<<FILL_P * FILL_BPP, 256, 0, stream>>>(src, dst, cursor, csr_src);
    k_sortrows<<<(NN + 255) / 256, 256, 0, stream>>>(rowptr, csr_src);

    // layers
    const float* hin = x;
    float* bufs[2] = {hA, hB};
    const int nblk_mv = (NN + 63) / 64;       // 1563 blocks, 64 nodes/block
    const int nblk_b  = (NN * 4 + 255) / 256; // 1563 blocks, one node per quad
    for (int i = 0; i < L; ++i) {
        float* hout = bufs[i & 1];
        k_gather<<<(NN + 3) / 4, 256, 0, stream>>>(hin, rowptr, csr_src, meanb);
        k_wt<<<(3 * D * D + 255) / 256, 256, 0, stream>>>(Wa + i * D * D, Wr + i * D * D,
                                                          Wl + i * D * D, wtbuf);
        k_matvec<<<nblk_mv, 512, 0, stream>>>(meanb, hin, hout, wtbuf,
                                              ba + i * D, bl + i * D);
        k_bnstats<<<GRID_A, 256, 0, stream>>>(hout, part);
        k_red_stats<<<128, 256, 0, stream>>>(part, stats + i * 128);
        k_layer_b<<<nblk_b, 256, 0, stream>>>(hout, stats + i * 128,
                                              gamma + i * D, beta + i * D,
                                              cbs + i * RVQ * CODES * D,
                                              xloc, ids, i, commit, (i == 0) ? 1 : 0);
        hin = hout;
    }

    // heads
    k_head<<<2048, 256, 0, stream>>>(xloc, Wp, bp, Wg, bg, pred, gnn);
}

// Round 12
// 802.892 us; speedup vs baseline: 1.0700x; 1.0700x over previous
//
#include <hip/hip_runtime.h>
#include <math.h>

#define NN 100000
#define NE 1000000
#define D 64
#define L 3
#define RVQ 3
#define CODES 16
#define BN_EPS 1e-5f
#define COMMIT_W 0.25f

#define GRID_A 2048   // blocks for bnstats kernel (fixed: partials + node mapping)

// ---------------- ws layout (in 4-byte units) ----------------
#define OFS_ROWPTR 0           // 100001 ints
#define OFS_CNT    100016      // 100000 ints
#define OFS_CURSOR 200032      // 100000 ints (reused as Wt scratch after CSR build)
#define OFS_BSUMS  300048      // 128 ints
#define OFS_BOFFS  300176      // 128 ints
#define OFS_STATS  300304      // 3*128 floats (sum[64],sumsq[64] per layer)
#define OFS_CSR    300800      // 1000000 ints
#define OFS_HA     1300800     // 6400000 floats
#define OFS_HB     7700800     // 6400000 floats
#define OFS_XLOC   14100800    // 6400000 floats
#define OFS_PART   20500800    // 2048*128 floats = 262144
// total = 20,762,944 * 4 B ~= 83 MB
// mean buffer lives in d_out's pred region (scratch until k_head overwrites).

// ---------------- d_out layout (floats) ----------------
#define OUT_PRED   0
#define OUT_COMMIT (NN * D)                       // 6,400,000
#define OUT_IDS    (NN * D + 1)                   // 6,400,001
#define OUT_GNN    (NN * D + 1 + NN * (L * RVQ))  // 7,300,001

static __device__ __forceinline__ float waveSum(float v) {
    #pragma unroll
    for (int off = 32; off; off >>= 1) v += __shfl_xor(v, off, 64);
    return v;
}

// DPP quad-permute helpers: value from lane^1 / lane^2 within each quad.
static __device__ __forceinline__ float qxor1(float v) {
    return __int_as_float(__builtin_amdgcn_mov_dpp(__float_as_int(v), 0xB1, 0xF, 0xF, 1));
}
static __device__ __forceinline__ float qxor2(float v) {
    return __int_as_float(__builtin_amdgcn_mov_dpp(__float_as_int(v), 0x4E, 0xF, 0xF, 1));
}

// ---------------- CSR build ----------------
__global__ void k_count(const int* __restrict__ dst, int* __restrict__ cnt) {
    int e = blockIdx.x * blockDim.x + threadIdx.x;
    if (e < NE) atomicAdd(&cnt[dst[e]], 1);
}

#define SCAN_B 1024
__global__ void k_scan1(const int* __restrict__ cnt, int* __restrict__ rowptr,
                        int* __restrict__ bsums) {
    __shared__ int sm[SCAN_B];
    int t = threadIdx.x;
    int i = blockIdx.x * SCAN_B + t;
    int v = (i < NN) ? cnt[i] : 0;
    sm[t] = v;
    __syncthreads();
    for (int off = 1; off < SCAN_B; off <<= 1) {
        int add = (t >= off) ? sm[t - off] : 0;
        __syncthreads();
        sm[t] += add;
        __syncthreads();
    }
    if (i < NN) rowptr[i + 1] = sm[t];
    if (t == SCAN_B - 1) bsums[blockIdx.x] = sm[t];
}

__global__ void k_scan2(const int* __restrict__ bsums, int* __restrict__ boffs, int nb) {
    __shared__ int sm[SCAN_B];
    int t = threadIdx.x;
    int orig = (t < nb) ? bsums[t] : 0;
    sm[t] = orig;
    __syncthreads();
    for (int off = 1; off < SCAN_B; off <<= 1) {
        int add = (t >= off) ? sm[t - off] : 0;
        __syncthreads();
        sm[t] += add;
        __syncthreads();
    }
    if (t < nb) boffs[t] = sm[t] - orig;  // exclusive
}

__global__ void k_scan3(int* __restrict__ rowptr, const int* __restrict__ boffs) {
    int i = blockIdx.x * SCAN_B + threadIdx.x;
    if (i < NN) rowptr[i + 1] += boffs[blockIdx.x];
    if (i == 0) rowptr[0] = 0;
}

__global__ void k_cursor(const int* __restrict__ rowptr, int* __restrict__ cursor) {
    int i = blockIdx.x * blockDim.x + threadIdx.x;
    if (i < NN) cursor[i] = rowptr[i];
}

// dst-range-partitioned fill (R11) + full parallelism (R12). R11 proved the
// partition mechanism (WRITE 69->35.8 MB) but cut the grid to 512 blocks ->
// 20% occupancy, and each thread's ~61 dependent atomic->store round-trips
// became the bottleneck (VALUBusy 1.8%, HBM 8.8%: pure latency-bound).
// FILL_BPP 64->256 restores 2048 blocks (~full occupancy, ~15 edges/thread)
// while keeping piece affinity (blockIdx&7 round-robins pieces onto XCDs)
// and the same per-piece L2-resident write slices. Read traffic is a
// per-piece scan -- independent of blocks-per-piece. Fill order within a
// row changes but k_sortrows canonicalizes -> outputs BIT-IDENTICAL.
#define FILL_P   8
#define FILL_BPP 256  // blocks per piece
__global__ __launch_bounds__(256) void k_fill(
    const int* __restrict__ src, const int* __restrict__ dst,
    int* __restrict__ cursor, int* __restrict__ csr_src) {
    int piece = blockIdx.x & (FILL_P - 1);      // same XCD for a given piece
    int bip   = blockIdx.x / FILL_P;
    int lo = piece * (NN / FILL_P);
    int hi = lo + (NN / FILL_P);
    int e0 = bip * 256 + threadIdx.x;
    const int stride = FILL_BPP * 256;
    for (int e = e0; e < NE; e += stride) {
        int d = __builtin_nontemporal_load(&dst[e]);
        if (d >= lo && d < hi) {
            int p = atomicAdd(&cursor[d], 1);
            csr_src[p] = __builtin_nontemporal_load(&src[e]);
        }
    }
}

// Canonicalize row order so the neighbor-sum order is deterministic.
__global__ void k_sortrows(const int* __restrict__ rowptr, int* __restrict__ csr) {
    int n = blockIdx.x * blockDim.x + threadIdx.x;
    if (n >= NN) return;
    int r0 = rowptr[n], r1 = rowptr[n + 1];
    for (int i = r0 + 1; i < r1; ++i) {
        int v = csr[i];
        int j = i - 1;
        while (j >= r0 && csr[j] > v) { csr[j + 1] = csr[j]; --j; }
        csr[j + 1] = v;
    }
}

// ---------------- Gather: mean of neighbor rows -> mean_out ----------------
__global__ __launch_bounds__(256) void k_gather(
    const float* __restrict__ h, const int* __restrict__ rowptr,
    const int* __restrict__ csr_src, float* __restrict__ mean_out) {
    int t = threadIdx.x;
    int lane = t & 63, wid = t >> 6;
    int n = blockIdx.x * 4 + wid;
    if (n >= NN) return;

    int r0 = rowptr[n], r1 = rowptr[n + 1];
    float s = 0.f;
    for (int base = r0; base < r1; base += 64) {
        int last = r1 - 1;
        int ii = base + lane;
        int idx = csr_src[(ii <= last) ? ii : last];  // coalesced, clamped
        int m = r1 - base;
        if (m > 64) m = 64;
        int j = 0;
        for (; j + 8 <= m; j += 8) {
            int i0 = __shfl(idx, j + 0, 64), i1 = __shfl(idx, j + 1, 64);
            int i2 = __shfl(idx, j + 2, 64), i3 = __shfl(idx, j + 3, 64);
            int i4 = __shfl(idx, j + 4, 64), i5 = __shfl(idx, j + 5, 64);
            int i6 = __shfl(idx, j + 6, 64), i7 = __shfl(idx, j + 7, 64);
            float v0 = h[i0 * D + lane], v1 = h[i1 * D + lane];
            float v2 = h[i2 * D + lane], v3 = h[i3 * D + lane];
            float v4 = h[i4 * D + lane], v5 = h[i5 * D + lane];
            float v6 = h[i6 * D + lane], v7 = h[i7 * D + lane];
            s += v0; s += v1; s += v2; s += v3;
            s += v4; s += v5; s += v6; s += v7;
        }
        for (; j + 4 <= m; j += 4) {
            int i0 = __shfl(idx, j + 0, 64), i1 = __shfl(idx, j + 1, 64);
            int i2 = __shfl(idx, j + 2, 64), i3 = __shfl(idx, j + 3, 64);
            float v0 = h[i0 * D + lane], v1 = h[i1 * D + lane];
            float v2 = h[i2 * D + lane], v3 = h[i3 * D + lane];
            s += v0; s += v1; s += v2; s += v3;
        }
        for (; j < m; ++j) {
            int i0 = __shfl(idx, j, 64);
            s += h[i0 * D + lane];
        }
    }
    float deg = (float)(r1 - r0);
    mean_out[n * D + lane] = s / fmaxf(deg, 1.0f);
}

// Weight transpose pre-pass: wt[m][o][k] = Wm[k*D+o], so per-output rows
// are contiguous for scalar (s_load) access. 48 KB per layer, ~2us.
__global__ void k_wt(const float* __restrict__ Wa, const float* __restrict__ Wr,
                     const float* __restrict__ Wl, float* __restrict__ wt) {
    int i = blockIdx.x * 256 + threadIdx.x;
    if (i >= 3 * D * D) return;
    int m = i >> 12;
    int o = (i >> 6) & 63;
    int k = i & 63;
    const float* W = (m == 0) ? Wa : (m == 1) ? Wr : Wl;
    wt[i] = W[k * D + o];
}

// ---------------- Matvec: SAGE transform + skip linear ----------------
// lane=node, weights scalar (SGPR), streamed activations (R10, passed):
// live set ~40 VGPR beats the stingiest allocator grant; DS 32 b128/thread;
// FMA order identical across rounds -> hp BIT-IDENTICAL.
__global__ __launch_bounds__(512) void k_matvec(
    const float* __restrict__ mean, const float* __restrict__ h,
    float* __restrict__ hp, const float* __restrict__ wt,
    const float* __restrict__ ba, const float* __restrict__ bl) {
    __shared__ alignas(16) float ls[64 * 132];  // 33792 B; reused by epilogue
    int t = threadIdx.x, lane = t & 63, wid = t >> 6;
    int tb = blockIdx.x * 64;

    // ---- stage 64 node rows of mean and h, coalesced float4 ----
    #pragma unroll
    for (int s = 0; s < 2; ++s) {
        int fid = s * 512 + t;          // 0..1023 float4 slots
        int node = fid >> 4, c = (fid & 15) * 4;
        int gn = tb + node; if (gn > NN - 1) gn = NN - 1;   // tail clamp
        float4 vm = *(const float4*)(mean + (size_t)gn * D + c);
        float4 vh = *(const float4*)(h    + (size_t)gn * D + c);
        *(float4*)&ls[node * 132 + c]      = vm;
        *(float4*)&ls[node * 132 + 64 + c] = vh;
    }
    __syncthreads();

    int ob = __builtin_amdgcn_readfirstlane(wid * 8);  // wave's o-base (uniform)

    float am[8], rm[8], lm[8];
    #pragma unroll
    for (int oi = 0; oi < 8; ++oi) { am[oi] = 0.f; rm[oi] = 0.f; lm[oi] = 0.f; }

    #pragma unroll 1
    for (int g = 0; g < 16; ++g) {      // k-groups of 4: act floats streamed
        float4 m4 = *(const float4*)&ls[lane * 132 + g * 4];
        float4 h4 = *(const float4*)&ls[lane * 132 + 64 + g * 4];
        #pragma unroll
        for (int oi = 0; oi < 8; ++oi) {
            const float* wa = wt +        (ob + oi) * D + g * 4;  // uniform
            const float* wr = wt + 4096 + (ob + oi) * D + g * 4;
            const float* wl = wt + 8192 + (ob + oi) * D + g * 4;
            am[oi] += m4.x * wa[0]; rm[oi] += h4.x * wr[0]; lm[oi] += h4.x * wl[0];
            am[oi] += m4.y * wa[1]; rm[oi] += h4.y * wr[1]; lm[oi] += h4.y * wl[1];
            am[oi] += m4.z * wa[2]; rm[oi] += h4.z * wr[2]; lm[oi] += h4.z * wl[2];
            am[oi] += m4.w * wa[3]; rm[oi] += h4.w * wr[3]; lm[oi] += h4.w * wl[3];
        }
    }
    __syncthreads();   // all act reads done before ls is overwritten

    // transpose sage/lm into LDS: writer lane = node; stride 65 -> bank
    // (lane + o) % 32, 2 lanes/bank = free
    #pragma unroll
    for (int oi = 0; oi < 8; ++oi) {
        float bav = ba[ob + oi];                   // uniform scalar
        float sage = am[oi] + bav + rm[oi];        // (am+bav)+rm, exact old order
        ls[lane * 65 + (ob + oi)]        = sage;
        ls[4160 + lane * 65 + (ob + oi)] = lm[oi];
    }
    __syncthreads();

    // epilogue: lane = o; wave handles 8 nodes; EXACT old butterfly + chain
    float blv = bl[lane];
    #pragma unroll
    for (int i = 0; i < 8; ++i) {
        int node = wid * 8 + i;
        float sage = ls[node * 65 + lane];
        float lv   = ls[4160 + node * 65 + lane];
        float ss = waveSum(sage * sage);
        float inv = 1.0f / (sqrtf(ss) + 1e-12f);
        float hpv = sage * inv + lv + blv;
        int gn = tb + node;
        if (gn < NN) hp[(size_t)gn * D + lane] = hpv;
    }
}

// BN stat partials over the finished hp buffer. Replicates the ORIGINAL
// k_matvec accumulation order exactly -> stats BIT-IDENTICAL.
__global__ __launch_bounds__(256) void k_bnstats(
    const float* __restrict__ hp, float* __restrict__ partials) {
    __shared__ float red[2][4][D];
    int t = threadIdx.x, lane = t & 63, wid = t >> 6;
    int wg = blockIdx.x * 4 + wid;
    const int wstep = GRID_A * 4;
    float accS = 0.f, accQ = 0.f;
    for (int n = wg; n < NN; n += wstep) {
        float hpv = hp[(size_t)n * D + lane];
        accS += hpv;
        accQ += hpv * hpv;
    }
    red[0][wid][lane] = accS;
    red[1][wid][lane] = accQ;
    __syncthreads();
    if (wid == 0) {
        float s0 = (red[0][0][lane] + red[0][1][lane]) + (red[0][2][lane] + red[0][3][lane]);
        float q0 = (red[1][0][lane] + red[1][1][lane]) + (red[1][2][lane] + red[1][3][lane]);
        partials[blockIdx.x * 128 + lane]      = s0;
        partials[blockIdx.x * 128 + 64 + lane] = q0;
    }
}

// Parallel deterministic reduction of BN stat partials.
__global__ __launch_bounds__(256) void k_red_stats(
    const float* __restrict__ part, float* __restrict__ stats) {
    __shared__ float sm[256];
    int c = blockIdx.x;      // 0..127
    int i = threadIdx.x;     // 0..255
    float s = 0.f;
    #pragma unroll
    for (int k = 0; k < 8; ++k)
        s += part[(size_t)(i * 8 + k) * 128 + c];
    sm[i] = s;
    __syncthreads();
    #pragma unroll
    for (int off = 128; off >= 1; off >>= 1) {
        if (i < off) sm[i] += sm[i + off];
        __syncthreads();
    }
    if (i == 0) stats[c] = sm[0];
}

// ---------------- Layer part B: BN + ReLU + x_local accumulate + residual VQ
// Quad-per-node scheme: residual in registers, DPP quad reduces, serial
// first-max argmax; bit-identical sims to the wave-per-node original.
#define CBSTRIDE 68
__global__ __launch_bounds__(256) void k_layer_b(
    float* __restrict__ hp,              // in: pre-BN h'; out: post-ReLU h
    const float* __restrict__ stats,
    const float* __restrict__ gamma, const float* __restrict__ beta,
    const float* __restrict__ cbs,       // [RVQ][CODES][D] for this layer
    float* __restrict__ x_local,
    float* __restrict__ ids_out,         // [NN][L*RVQ] region base
    int layer, float* __restrict__ commit, int first_layer) {
    __shared__ alignas(16) float scb[RVQ * CODES * CBSTRIDE];
    __shared__ alignas(16) float sscale[D];
    __shared__ alignas(16) float sshift[D];
    __shared__ float sred[4];
    int t = threadIdx.x, lane = t & 63, wid = t >> 6;

    // normalize codebook rows into LDS (identical math to before)
    for (int row = wid; row < RVQ * CODES; row += 4) {
        float v = cbs[row * D + lane];
        float ss = waveSum(v * v);
        scb[row * CBSTRIDE + lane] = v / (sqrtf(ss) + 1e-12f);
    }
    // BN scale/shift per channel
    if (t < D) {
        float mu = stats[t] * (1.0f / NN);
        float var = stats[64 + t] * (1.0f / NN) - mu * mu;
        float scale = rsqrtf(var + BN_EPS) * gamma[t];
        sscale[t] = scale;
        sshift[t] = beta[t] - mu * scale;
    }
    __syncthreads();

    int gid = blockIdx.x * 256 + t;
    int node = gid >> 2;      // one node per quad of lanes
    int part = t & 3;         // which 16-channel slice this lane owns
    float closs = 0.f;

    if (node < NN) {
        float res[16];
        size_t base = (size_t)node * D + part * 16;
        const float4* hr = (const float4*)(hp + base);
        float4* hw = (float4*)(hp + base);
        float4* xw = (float4*)(x_local + base);
        const float4* scp = (const float4*)(sscale + part * 16);
        const float4* shp = (const float4*)(sshift + part * 16);

        #pragma unroll
        for (int i = 0; i < 4; ++i) {
            float4 v = hr[i];
            float4 sc = scp[i], sh = shp[i];
            float4 hn;
            hn.x = fmaxf(v.x * sc.x + sh.x, 0.f);
            hn.y = fmaxf(v.y * sc.y + sh.y, 0.f);
            hn.z = fmaxf(v.z * sc.z + sh.z, 0.f);
            hn.w = fmaxf(v.w * sc.w + sh.w, 0.f);
            hw[i] = hn;
            if (first_layer) {
                xw[i] = hn;
            } else {
                float4 xl = xw[i];
                xl.x += hn.x; xl.y += hn.y; xl.z += hn.z; xl.w += hn.w;
                xw[i] = xl;
            }
            res[4 * i + 0] = hn.x; res[4 * i + 1] = hn.y;
            res[4 * i + 2] = hn.z; res[4 * i + 3] = hn.w;
        }

        int bis[RVQ];
        #pragma unroll
        for (int r = 0; r < RVQ; ++r) {
            float sims[CODES];
            #pragma unroll
            for (int j = 0; j < CODES; ++j) {
                const float* cr = &scb[(r * CODES + j) * CBSTRIDE + part * 16];
                float4 c0 = *(const float4*)(cr + 0);
                float4 c1 = *(const float4*)(cr + 4);
                float4 c2 = *(const float4*)(cr + 8);
                float4 c3 = *(const float4*)(cr + 12);
                float a = res[0] * c0.x;
                a += res[1] * c0.y;  a += res[2] * c0.z;  a += res[3] * c0.w;
                a += res[4] * c1.x;  a += res[5] * c1.y;  a += res[6] * c1.z;  a += res[7] * c1.w;
                a += res[8] * c2.x;  a += res[9] * c2.y;  a += res[10] * c2.z; a += res[11] * c2.w;
                a += res[12] * c3.x; a += res[13] * c3.y; a += res[14] * c3.z; a += res[15] * c3.w;
                float b = a + qxor1(a);
                sims[j] = b + qxor2(b);
            }
            float bv = sims[0];
            int bi = 0;
            #pragma unroll
            for (int j = 1; j < CODES; ++j)
                if (sims[j] > bv) { bv = sims[j]; bi = j; }

            const float* qr = &scb[(r * CODES + bi) * CBSTRIDE + part * 16];
            #pragma unroll
            for (int i = 0; i < 4; ++i) {
                float4 q = *(const float4*)(qr + 4 * i);
                float d0 = q.x - res[4 * i + 0]; closs += d0 * d0; res[4 * i + 0] = -d0;
                float d1 = q.y - res[4 * i + 1]; closs += d1 * d1; res[4 * i + 1] = -d1;
                float d2 = q.z - res[4 * i + 2]; closs += d2 * d2; res[4 * i + 2] = -d2;
                float d3 = q.w - res[4 * i + 3]; closs += d3 * d3; res[4 * i + 3] = -d3;
            }
            bis[r] = bi;
        }
        if (part == 0) {
            ids_out[(size_t)node * (L * RVQ) + layer * RVQ + 0] = (float)bis[0];
            ids_out[(size_t)node * (L * RVQ) + layer * RVQ + 1] = (float)bis[1];
            ids_out[(size_t)node * (L * RVQ) + layer * RVQ + 2] = (float)bis[2];
        }
    }

    closs = waveSum(closs);
    if (lane == 0) sred[wid] = closs;
    __syncthreads();
    if (t == 0) {
        float tot = (sred[0] + sred[1]) + (sred[2] + sred[3]);
        atomicAdd(commit, tot * (COMMIT_W / (float)(NN * D)));
    }
}

// ---------------- Heads ----------------
__global__ __launch_bounds__(256, 2) void k_head(
    const float* __restrict__ x_local,
    const float* __restrict__ Wp, const float* __restrict__ bp,
    const float* __restrict__ Wg, const float* __restrict__ bg,
    float* __restrict__ pred, float* __restrict__ gnn) {
    int t = threadIdx.x, lane = t & 63, wid = t >> 6;
    int jsafe = (lane < 9) ? lane : 0;

    float wp[D], wg[D];
    #pragma unroll
    for (int k = 0; k < D; ++k) {
        wp[k] = Wp[k * D + lane];
        wg[k] = Wg[k * 9 + jsafe];
    }
    float bpv = bp[lane], bgv = bg[jsafe];

    int w = blockIdx.x * 4 + wid;
    int wstep = gridDim.x * 4;
    for (int n = w; n < NN; n += wstep) {
        int nu = __builtin_amdgcn_readfirstlane(n);
        const float4* xrow = (const float4*)(x_local + (size_t)nu * D);
        float p = 0.f, g = 0.f;
        #pragma unroll
        for (int j = 0; j < 16; ++j) {
            float4 x4 = xrow[j];
            p += x4.x * wp[4 * j + 0]; g += x4.x * wg[4 * j + 0];
            p += x4.y * wp[4 * j + 1]; g += x4.y * wg[4 * j + 1];
            p += x4.z * wp[4 * j + 2]; g += x4.z * wg[4 * j + 2];
            p += x4.w * wp[4 * j + 3]; g += x4.w * wg[4 * j + 3];
        }
        pred[(size_t)n * D + lane] = p + bpv;
        if (lane < 9) gnn[(size_t)n * 9 + lane] = g + bgv;
    }
}

extern "C" void kernel_launch(void* const* d_in, const int* in_sizes, int n_in,
                              void* d_out, int out_size, void* d_ws, size_t ws_size,
                              hipStream_t stream) {
    const float* x   = (const float*)d_in[0];
    const int* ei    = (const int*)d_in[1];
    const float* Wa  = (const float*)d_in[2];
    const float* ba  = (const float*)d_in[3];
    const float* Wr  = (const float*)d_in[4];
    const float* Wl  = (const float*)d_in[5];
    const float* bl  = (const float*)d_in[6];
    const float* gamma = (const float*)d_in[7];
    const float* beta  = (const float*)d_in[8];
    const float* cbs = (const float*)d_in[9];
    const float* Wp  = (const float*)d_in[10];
    const float* bp  = (const float*)d_in[11];
    const float* Wg  = (const float*)d_in[12];
    const float* bg  = (const float*)d_in[13];

    const int* src = ei;
    const int* dst = ei + NE;

    int*   ws_i  = (int*)d_ws;
    float* ws_f  = (float*)d_ws;
    int* rowptr  = ws_i + OFS_ROWPTR;
    int* cnt     = ws_i + OFS_CNT;
    int* cursor  = ws_i + OFS_CURSOR;
    int* bsums   = ws_i + OFS_BSUMS;
    int* boffs   = ws_i + OFS_BOFFS;
    float* stats = ws_f + OFS_STATS;
    int* csr_src = ws_i + OFS_CSR;
    float* hA    = ws_f + OFS_HA;
    float* hB    = ws_f + OFS_HB;
    float* xloc  = ws_f + OFS_XLOC;
    float* part  = ws_f + OFS_PART;
    float* wtbuf = ws_f + OFS_CURSOR;   // cursor scratch reused after CSR build

    float* out    = (float*)d_out;
    float* pred   = out + OUT_PRED;
    float* commit = out + OUT_COMMIT;
    float* ids    = out + OUT_IDS;
    float* gnn    = out + OUT_GNN;

    // mean buffer: reuse the pred region of d_out as scratch during the
    // layer loop (k_head fully overwrites it at the end).
    float* meanb = pred;

    hipMemsetAsync(cnt, 0, NN * sizeof(int), stream);
    hipMemsetAsync(commit, 0, sizeof(float), stream);

    // CSR build
    k_count<<<(NE + 255) / 256, 256, 0, stream>>>(dst, cnt);
    int nscan = (NN + SCAN_B - 1) / SCAN_B;  // 98
    k_scan1<<<nscan, SCAN_B, 0, stream>>>(cnt, rowptr, bsums);
    k_scan2<<<1, SCAN_B, 0, stream>>>(bsums, boffs, nscan);
    k_scan3<<<nscan, SCAN_B, 0, stream>>>(rowptr, boffs);
    k_cursor<<<(NN + 1023) / 1024, 1024, 0, stream>>>(rowptr, cursor);
    k_fill<<<FILL_P * FILL_BPP, 256, 0, stream>>>(src, dst, cursor, csr_src);
    k_sortrows<<<(NN + 255) / 256, 256, 0, stream>>>(rowptr, csr_src);

    // layers
    const float* hin = x;
    float* bufs[2] = {hA, hB};
    const int nblk_mv = (NN + 63) / 64;       // 1563 blocks, 64 nodes/block
    const int nblk_b  = (NN * 4 + 255) / 256; // 1563 blocks, one node per quad
    for (int i = 0; i < L; ++i) {
        float* hout = bufs[i & 1];
        k_gather<<<(NN + 3) / 4, 256, 0, stream>>>(hin, rowptr, csr_src, meanb);
        k_wt<<<(3 * D * D + 255) / 256, 256, 0, stream>>>(Wa + i * D * D, Wr + i * D * D,
                                                          Wl + i * D * D, wtbuf);
        k_matvec<<<nblk_mv, 512, 0, stream>>>(meanb, hin, hout, wtbuf,
                                              ba + i * D, bl + i * D);
        k_bnstats<<<GRID_A, 256, 0, stream>>>(hout, part);
        k_red_stats<<<128, 256, 0, stream>>>(part, stats + i * 128);
        k_layer_b<<<nblk_b, 256, 0, stream>>>(hout, stats + i * 128,
                                              gamma + i * D, beta + i * D,
                                              cbs + i * RVQ * CODES * D,
                                              xloc, ids, i, commit, (i == 0) ? 1 : 0);
        hin = hout;
    }

    // heads
    k_head<<<2048, 256, 0, stream>>>(xloc, Wp, bp, Wg, bg, pred, gnn);
}